// Round 1
// baseline (322.992 us; speedup 1.0000x reference)
//
#include <hip/hip_runtime.h>
#include <hip/hip_bf16.h>

#define D 64
#define NUM_GENRES 18

// Pre-kernel: per-genre-row sums of genre_emb [18,64] -> rowsum[18] in d_ws.
__global__ void genre_rowsum_kernel(const float* __restrict__ genre_emb,
                                    float* __restrict__ rowsum) {
    int j = threadIdx.x;
    if (j < NUM_GENRES) {
        float s = 0.f;
#pragma unroll
        for (int d = 0; d < D; ++d) s += genre_emb[j * D + d];
        rowsum[j] = s;
    }
}

// One 64-lane wave per output row. Lane = embedding dim.
__global__ __launch_bounds__(256) void mf_kernel(
    const int* __restrict__ user_id, const int* __restrict__ item_id,
    const int* __restrict__ occupation, const int* __restrict__ genre,
    const float* __restrict__ user_emb, const float* __restrict__ user_b,
    const float* __restrict__ item_emb, const float* __restrict__ item_b,
    const float* __restrict__ occ_emb, const float* __restrict__ occ_b,
    const float* __restrict__ genre_b, const float* __restrict__ rowsum,
    float* __restrict__ out, int B) {

    int wave = (int)((blockIdx.x * blockDim.x + threadIdx.x) >> 6);
    int lane = threadIdx.x & 63;
    if (wave >= B) return;
    const int b = wave;

    const int uid = user_id[b];
    const int iid = item_id[b];
    const int oc  = occupation[b];

    // Coalesced 256B gathers: lane d reads dim d of each embedding row.
    const float q = user_emb[(size_t)uid * D + lane];
    const float i = item_emb[(size_t)iid * D + lane];
    const float o = occ_emb[(size_t)oc * D + lane];

    float s1 = q * (i + o);   // dot(Q,I) + dot(Q,O) partial
    float s2 = i;             // sum(I) partial

    // Genre mask partials (lanes 0..17 only).
    float gsum = 0.f, gbias = 0.f, gcnt = 0.f;
    if (lane < NUM_GENRES) {
        if (genre[b * NUM_GENRES + lane] != 0) {
            gsum  = rowsum[lane];
            gbias = genre_b[lane];
            gcnt  = 1.f;
        }
    }

    // 64-lane butterfly reduction of 5 values.
#pragma unroll
    for (int off = 32; off > 0; off >>= 1) {
        s1    += __shfl_xor(s1, off, 64);
        s2    += __shfl_xor(s2, off, 64);
        gsum  += __shfl_xor(gsum, off, 64);
        gbias += __shfl_xor(gbias, off, 64);
        gcnt  += __shfl_xor(gcnt, off, 64);
    }

    if (lane == 0) {
        const float g  = gsum / (gcnt * (float)D);
        const float bg = gbias / gcnt;
        out[b] = s1 + g * s2 + user_b[uid] + item_b[iid] + occ_b[oc] + bg;
    }
}

extern "C" void kernel_launch(void* const* d_in, const int* in_sizes, int n_in,
                              void* d_out, int out_size, void* d_ws, size_t ws_size,
                              hipStream_t stream) {
    const int*   user_id    = (const int*)d_in[0];
    const int*   item_id    = (const int*)d_in[1];
    const int*   occupation = (const int*)d_in[2];
    const int*   genre      = (const int*)d_in[3];
    const float* user_emb   = (const float*)d_in[4];
    const float* user_b     = (const float*)d_in[5];
    const float* item_emb   = (const float*)d_in[6];
    const float* item_b     = (const float*)d_in[7];
    const float* occ_emb    = (const float*)d_in[8];
    const float* occ_b      = (const float*)d_in[9];
    const float* genre_emb  = (const float*)d_in[10];
    const float* genre_b    = (const float*)d_in[11];

    float* out    = (float*)d_out;
    float* rowsum = (float*)d_ws;   // 18 floats of scratch

    const int B = in_sizes[0];

    genre_rowsum_kernel<<<1, 64, 0, stream>>>(genre_emb, rowsum);

    const int waves_per_block = 256 / 64;
    const int grid = (B + waves_per_block - 1) / waves_per_block;
    mf_kernel<<<grid, 256, 0, stream>>>(user_id, item_id, occupation, genre,
                                        user_emb, user_b, item_emb, item_b,
                                        occ_emb, occ_b, genre_b, rowsum,
                                        out, B);
}

// Round 2
// 320.003 us; speedup vs baseline: 1.0093x; 1.0093x over previous
//
#include <hip/hip_runtime.h>
#include <hip/hip_bf16.h>

#define D 64
#define NUM_GENRES 18

// One fused kernel. 16 lanes per row (float4 per lane), 4 rows per wave.
// genre_emb (18x64 = 4.6 KB) is L1-resident; each lane accumulates its
// 4 dims over the row's selected genres via a ballot-derived bitmask,
// eliminating the separate rowsum pre-kernel.
__global__ __launch_bounds__(256) void mf_fused(
    const int* __restrict__ user_id, const int* __restrict__ item_id,
    const int* __restrict__ occupation, const int* __restrict__ genre,
    const float* __restrict__ user_emb, const float* __restrict__ user_b,
    const float* __restrict__ item_emb, const float* __restrict__ item_b,
    const float* __restrict__ occ_emb, const float* __restrict__ occ_b,
    const float* __restrict__ genre_emb, const float* __restrict__ genre_b,
    float* __restrict__ out, int B) {

    const int t   = blockIdx.x * blockDim.x + threadIdx.x;
    const int row = t >> 4;              // 16 lanes per row
    const int l   = threadIdx.x & 15;    // lane within group
    const bool active = (row < B);

    int uid = 0, iid = 0, oc = 0;
    if (active) {
        uid = user_id[row];
        iid = item_id[row];
        oc  = occupation[row];
    }

    // Genre flags: lane l covers genre j=l (0..15); lanes 0,1 also j=16,17.
    int fa = 0, fb = 0;
    if (active) {
        fa = genre[row * NUM_GENRES + l];
        if (l < 2) fb = genre[row * NUM_GENRES + 16 + l];
    }
    unsigned long long ba = __ballot(fa != 0);
    unsigned long long bb = __ballot(fb != 0);
    const int gsh = (threadIdx.x & 63) & ~15;   // group's base lane in wave
    const unsigned int mask =
        (unsigned int)((ba >> gsh) & 0xFFFFull) |
        ((unsigned int)((bb >> gsh) & 0x3ull) << 16);   // 18-bit row mask

    const float4* ue4 = (const float4*)user_emb;
    const float4* ie4 = (const float4*)item_emb;
    const float4* oe4 = (const float4*)occ_emb;
    const float4* ge4 = (const float4*)genre_emb;

    float4 q  = make_float4(0.f, 0.f, 0.f, 0.f);
    float4 i4 = q, o4 = q;
    if (active) {
        q  = ue4[(size_t)uid * 16 + l];   // 16 lanes x 16 B = one 256 B txn
        i4 = ie4[(size_t)iid * 16 + l];
        o4 = oe4[(size_t)oc  * 16 + l];
    }

    // Sum selected genre_emb rows (L1 hits), lane's 4 dims.
    float4 gacc = make_float4(0.f, 0.f, 0.f, 0.f);
    unsigned int m = mask;
    while (m) {
        int j = __builtin_ctz(m);
        m &= m - 1;
        float4 e = ge4[j * 16 + l];
        gacc.x += e.x; gacc.y += e.y; gacc.z += e.z; gacc.w += e.w;
    }

    float s1 = q.x*(i4.x+o4.x) + q.y*(i4.y+o4.y) + q.z*(i4.z+o4.z) + q.w*(i4.w+o4.w);
    float si = i4.x + i4.y + i4.z + i4.w;
    float sg = gacc.x + gacc.y + gacc.z + gacc.w;
    float gb = 0.f;
    if (active) {
        if (fa)           gb += genre_b[l];
        if (l < 2 && fb)  gb += genre_b[16 + l];
    }

    // 4-step butterfly within each 16-lane group (xor masks < 16 stay in-group).
#pragma unroll
    for (int off = 8; off > 0; off >>= 1) {
        s1 += __shfl_xor(s1, off, 64);
        si += __shfl_xor(si, off, 64);
        sg += __shfl_xor(sg, off, 64);
        gb += __shfl_xor(gb, off, 64);
    }

    if (active && l == 0) {
        const float cnt = (float)__builtin_popcount(mask);
        const float g   = sg / (cnt * (float)D);
        out[row] = s1 + g * si + user_b[uid] + item_b[iid] + occ_b[oc] + gb / cnt;
    }
}

extern "C" void kernel_launch(void* const* d_in, const int* in_sizes, int n_in,
                              void* d_out, int out_size, void* d_ws, size_t ws_size,
                              hipStream_t stream) {
    const int*   user_id    = (const int*)d_in[0];
    const int*   item_id    = (const int*)d_in[1];
    const int*   occupation = (const int*)d_in[2];
    const int*   genre      = (const int*)d_in[3];
    const float* user_emb   = (const float*)d_in[4];
    const float* user_b     = (const float*)d_in[5];
    const float* item_emb   = (const float*)d_in[6];
    const float* item_b     = (const float*)d_in[7];
    const float* occ_emb    = (const float*)d_in[8];
    const float* occ_b      = (const float*)d_in[9];
    const float* genre_emb  = (const float*)d_in[10];
    const float* genre_b    = (const float*)d_in[11];

    float* out = (float*)d_out;
    const int B = in_sizes[0];

    const int threads = 256;
    const int grid = (B * 16 + threads - 1) / threads;   // 16 lanes per row
    mf_fused<<<grid, threads, 0, stream>>>(user_id, item_id, occupation, genre,
                                           user_emb, user_b, item_emb, item_b,
                                           occ_emb, occ_b, genre_emb, genre_b,
                                           out, B);
}